// Round 2
// baseline (278.883 us; speedup 1.0000x reference)
//
#include <hip/hip_runtime.h>
#include <hip/hip_cooperative_groups.h>
#include <math.h>

namespace cg = cooperative_groups;

#define EPS 1e-8f

typedef short bf16x8 __attribute__((ext_vector_type(8)));
typedef short bf16x4 __attribute__((ext_vector_type(4)));
typedef float f32x4  __attribute__((ext_vector_type(4)));

// fp32 -> bf16 bits, round-to-nearest-even
__device__ __forceinline__ short f2bf(float f) {
    union { float fv; unsigned u; } v; v.fv = f;
    unsigned r = v.u + 0x7fffu + ((v.u >> 16) & 1u);
    return (short)(r >> 16);
}
__device__ __forceinline__ bf16x8 pack8(float4 a, float4 b) {
    bf16x8 p;
    p[0] = f2bf(a.x); p[1] = f2bf(a.y); p[2] = f2bf(a.z); p[3] = f2bf(a.w);
    p[4] = f2bf(b.x); p[5] = f2bf(b.y); p[6] = f2bf(b.z); p[7] = f2bf(b.w);
    return p;
}

// ---------------------------------------------------------------------------
// Single cooperative kernel, 512 blocks x 256 threads = 2048 waves
// (2 waves/SIMD).  Phases separated by grid.sync():
//   P1: proj + normalize + quaternion-pair expand  (2048 16x16 tiles)
//   P2: logits E = exp(dot/1024), E^T, partial row sums (2048 16x16 tiles)
//   P3: finish softmax denom; bf16 transposes txtT, visST (rinv folded)
//   P4: outputs = base + h * (attn-product)        (2048 16x16 tiles)
// All MFMA operands loaded straight from global (bf16 fragment layout).
// C/D layout: col = lane&15, row = (lane>>4)*4 + reg.
// ---------------------------------------------------------------------------
__global__ __launch_bounds__(256, 2) void mega_kernel(
    const float* __restrict__ vis, const float* __restrict__ txt,
    const float* __restrict__ Wv, const float* __restrict__ bv,
    const float* __restrict__ Wt, const float* __restrict__ bt,
    const float* __restrict__ hptr,
    short* __restrict__ expq, short* __restrict__ E, short* __restrict__ ET,
    float* __restrict__ rs, float* __restrict__ rinv,
    short* __restrict__ txtT, short* __restrict__ visST,
    float* __restrict__ outv, float* __restrict__ outt)
{
    cg::grid_group grid = cg::this_grid();
    const int t = threadIdx.x, lane = t & 63, wave = t >> 6;
    const int w = blockIdx.x * 4 + wave;          // 0..2047
    const int mrow = lane & 15, quad = lane >> 4;

    // ---------------- P1: proj + normalize + expand ----------------
    {
        const int rt = w >> 4;                    // 0..127 (16-row tiles / 2048 rows)
        const int ct = w & 15;                    // 0..15  (16-col tiles / 256 cols)
        const int which = rt >> 6;
        const int r0 = (rt & 63) * 16, c0 = ct * 16;
        const float* X    = which ? txt : vis;
        const float* W    = which ? Wt : Wv;
        const float* bias = which ? bt : bv;
        short* Eo = expq + which * 1024 * 1024;

        const float* Arow = X + (r0 + mrow) * 256 + 8 * quad;
        const float* Brow = W + (c0 + mrow) * 256 + 8 * quad;

        f32x4 acc = {};
        #pragma unroll 2
        for (int k0 = 0; k0 < 256; k0 += 32) {
            float4 a0 = *(const float4*)(Arow + k0);
            float4 a1 = *(const float4*)(Arow + k0 + 4);
            float4 b0 = *(const float4*)(Brow + k0);
            float4 b1 = *(const float4*)(Brow + k0 + 4);
            bf16x8 af = pack8(a0, a1);
            bf16x8 bf = pack8(b0, b1);
            acc = __builtin_amdgcn_mfma_f32_16x16x32_bf16(af, bf, acc, 0, 0, 0);
        }

        const int col  = c0 + mrow;
        const float bb = bias[col];
        const int head = col >> 2;
        const int qbase = lane & ~3;
        #pragma unroll
        for (int reg = 0; reg < 4; ++reg) {
            const int row = r0 + quad * 4 + reg;
            float v = acc[reg] + bb;
            float s = v * v;
            s += __shfl_xor(s, 1, 64);
            s += __shfl_xor(s, 2, 64);
            float q = v * (1.f / (sqrtf(s) + EPS));
            float q0 = __shfl(q, qbase + 0, 64);
            float q1 = __shfl(q, qbase + 1, 64);
            float q2 = __shfl(q, qbase + 2, 64);
            float q3 = __shfl(q, qbase + 3, 64);
            bf16x4 p;
            p[0] = f2bf(q * q0); p[1] = f2bf(q * q1);
            p[2] = f2bf(q * q2); p[3] = f2bf(q * q3);
            *(bf16x4*)(Eo + row * 1024 + head * 16 + (col & 3) * 4) = p;
        }
    }
    grid.sync();

    // ---------------- P2: logits + E^T + partial row sums ----------------
    {
        const int b  = w >> 10;
        const int nt = (w >> 5) & 31;
        const int mt = w & 31;
        const int r0 = nt * 16, c0 = mt * 16;

        const short* Ar = expq + (b * 512 + r0 + mrow) * 1024 + 8 * quad;
        const short* Br = expq + (1024 + b * 512 + c0 + mrow) * 1024 + 8 * quad;

        f32x4 acc = {};
        #pragma unroll 8
        for (int k0 = 0; k0 < 1024; k0 += 32) {
            bf16x8 a  = *(const bf16x8*)(Ar + k0);
            bf16x8 bf = *(const bf16x8*)(Br + k0);
            acc = __builtin_amdgcn_mfma_f32_16x16x32_bf16(a, bf, acc, 0, 0, 0);
        }

        float e[4];
        bf16x4 pe;
        const int col = c0 + mrow;
        #pragma unroll
        for (int reg = 0; reg < 4; ++reg) {
            e[reg] = __expf(acc[reg] * (1.f / 1024.f));
            pe[reg] = f2bf(e[reg]);
            const int row = r0 + quad * 4 + reg;
            E[(b * 512 + row) * 512 + col] = pe[reg];
        }
        // transposed store: 4 consecutive rows -> one bf16x4
        *(bf16x4*)(ET + (b * 512 + col) * 512 + r0 + quad * 4) = pe;
        // partial sums over this wave's 16 cols
        #pragma unroll
        for (int reg = 0; reg < 4; ++reg) {
            float p = e[reg];
            p += __shfl_xor(p, 1, 64);
            p += __shfl_xor(p, 2, 64);
            p += __shfl_xor(p, 4, 64);
            p += __shfl_xor(p, 8, 64);
            if (mrow == 0) {
                const int row = r0 + quad * 4 + reg;
                rs[(b * 512 + row) * 32 + mt] = p;
            }
        }
    }
    grid.sync();

    // ---------------- P3: softmax denom + bf16 transposes ----------------
    {
        const int bx = blockIdx.x;
        if (bx < 256) {
            const int mat = bx >> 7;              // 0 = txt, 1 = vis
            const int b   = (bx >> 6) & 1;
            const int m0  = (bx & 63) * 8;

            __shared__ float rsc[8];
            if (mat == 1) {
                if (t < 8) {
                    const float* p = rs + (b * 512 + m0 + t) * 32;
                    float s = 0.f;
                    #pragma unroll
                    for (int i = 0; i < 32; ++i) s += p[i];
                    const float ri = 1.f / s;
                    rsc[t] = ri;
                    rinv[b * 512 + m0 + t] = ri;
                }
                __syncthreads();
            }

            const float* src = (mat ? vis : txt) + (b * 512 + m0) * 256 + t;
            short* dst = (mat ? visST : txtT) + (b * 256 + t) * 512 + m0;

            bf16x8 v0;
            #pragma unroll
            for (int i = 0; i < 8; ++i) {
                float a = src[i * 256];
                if (mat) a *= rsc[i];
                v0[i] = f2bf(a);
            }
            *(bf16x8*)dst = v0;
        }
    }
    grid.sync();

    // ---------------- P4: outputs ----------------
    {
        const int which = w >> 10;
        const int b     = (w >> 9) & 1;
        const int nt    = (w >> 4) & 31;
        const int dt    = w & 15;
        const int r0 = nt * 16, c0 = dt * 16;
        const float hv = hptr[0];

        const short* Ar = (which ? ET : E) + (b * 512 + r0 + mrow) * 512 + 8 * quad;
        const short* Br = (which ? visST : txtT) + (b * 256 + c0 + mrow) * 512 + 8 * quad;
        const float* base = (which ? txt : vis) + (b * 512 + r0) * 256;
        float*       out  = (which ? outt : outv) + (b * 512 + r0) * 256;

        f32x4 acc = {};
        #pragma unroll 8
        for (int k0 = 0; k0 < 512; k0 += 32) {
            bf16x8 a  = *(const bf16x8*)(Ar + k0);
            bf16x8 bf = *(const bf16x8*)(Br + k0);
            acc = __builtin_amdgcn_mfma_f32_16x16x32_bf16(a, bf, acc, 0, 0, 0);
        }

        const int col = c0 + mrow;
        #pragma unroll
        for (int reg = 0; reg < 4; ++reg) {
            const int row = quad * 4 + reg;
            const float scale = which ? hv : hv * rinv[b * 512 + r0 + row];
            out[row * 256 + col] = fmaf(scale, acc[reg], base[row * 256 + col]);
        }
    }
}

// ---------------------------------------------------------------------------
extern "C" void kernel_launch(void* const* d_in, const int* in_sizes, int n_in,
                              void* d_out, int out_size, void* d_ws, size_t ws_size,
                              hipStream_t stream)
{
    const float* vis = (const float*)d_in[0];
    const float* txt = (const float*)d_in[1];
    const float* Wv  = (const float*)d_in[2];
    const float* bv  = (const float*)d_in[3];
    const float* Wt  = (const float*)d_in[4];
    const float* bt  = (const float*)d_in[5];
    const float* h   = (const float*)d_in[6];

    float* outv = (float*)d_out;                  // 2*512*256
    float* outt = (float*)d_out + 2 * 512 * 256;

    short* expq  = (short*)d_ws;                  // 2048 x 1024 bf16 (4 MB)
    short* E     = expq + 2048 * 1024;            // 1024 x 512 bf16 (1 MB)
    short* ET    = E + 1024 * 512;                // 1024 x 512 bf16 (1 MB)
    float* rs    = (float*)(ET + 1024 * 512);     // 1024 x 32 fp32 (128 KB)
    float* rinv  = rs + 1024 * 32;                // 1024 fp32 (4 KB)
    short* txtT  = (short*)(rinv + 1024);         // 2 x 256 x 512 bf16 (0.5 MB)
    short* visST = txtT + 2 * 256 * 512;          // 2 x 256 x 512 bf16 (0.5 MB)

    void* args[] = {
        (void*)&vis, (void*)&txt, (void*)&Wv, (void*)&bv, (void*)&Wt, (void*)&bt,
        (void*)&h, (void*)&expq, (void*)&E, (void*)&ET, (void*)&rs, (void*)&rinv,
        (void*)&txtT, (void*)&visST, (void*)&outv, (void*)&outt
    };
    hipLaunchCooperativeKernel(mega_kernel, dim3(512), dim3(256), args, 0, stream);
}

// Round 3
// 93.577 us; speedup vs baseline: 2.9803x; 2.9803x over previous
//
#include <hip/hip_runtime.h>
#include <math.h>

#define EPS 1e-8f

typedef short bf16x8 __attribute__((ext_vector_type(8)));
typedef short bf16x4 __attribute__((ext_vector_type(4)));
typedef float f32x4  __attribute__((ext_vector_type(4)));

// fp32 -> bf16 bits, round-to-nearest-even
__device__ __forceinline__ short f2bf(float f) {
    union { float fv; unsigned u; } v; v.fv = f;
    unsigned r = v.u + 0x7fffu + ((v.u >> 16) & 1u);
    return (short)(r >> 16);
}
__device__ __forceinline__ bf16x8 pack8(float4 a, float4 b) {
    bf16x8 p;
    p[0] = f2bf(a.x); p[1] = f2bf(a.y); p[2] = f2bf(a.z); p[3] = f2bf(a.w);
    p[4] = f2bf(b.x); p[5] = f2bf(b.y); p[6] = f2bf(b.z); p[7] = f2bf(b.w);
    return p;
}

// ---------------------------------------------------------------------------
// K1: proj + normalize + fused quaternion-pair expand.
// Tile 16 rows x 64 cols, 4 waves (wave w -> cols 16w..16w+15), kt=64, K=256.
// grid (64, 4, 2) = 512 blocks -> 2 blocks/CU, 8 waves/CU.
// Double-buffered LDS, ONE barrier per K-step.
// C/D layout: col = lane&15, row = (lane>>4)*4 + reg.
// ---------------------------------------------------------------------------
__global__ __launch_bounds__(256, 2) void proj_expand_kernel(
    const float* __restrict__ vis, const float* __restrict__ txt,
    const float* __restrict__ Wv, const float* __restrict__ bv,
    const float* __restrict__ Wt, const float* __restrict__ bt,
    short* __restrict__ expq)
{
    const int which = blockIdx.z;
    const float* X    = which ? txt : vis;
    const float* W    = which ? Wt : Wv;
    const float* bias = which ? bt : bv;
    short* Eo = expq + which * 1024 * 1024;

    const int r0 = blockIdx.x * 16;
    const int c0 = blockIdx.y * 64;
    const int t = threadIdx.x, lane = t & 63, wave = t >> 6;
    const int wc = 16 * wave;
    const int mrow = lane & 15, quad = lane >> 4;

    __shared__ __align__(16) short As[2][16][72];
    __shared__ __align__(16) short Bs[2][64][72];

    const int srow = t >> 3, skg = t & 7;
    float4 xa, xb, wa0, wb0, wa1, wb1;

    // prologue: load + write tile 0
    if (t < 128) {
        const float* xp = X + (r0 + srow) * 256 + 8 * skg;
        xa = *(const float4*)xp; xb = *(const float4*)(xp + 4);
    }
    {
        const float* wp0 = W + (c0 + srow) * 256 + 8 * skg;
        const float* wp1 = wp0 + 32 * 256;
        wa0 = *(const float4*)wp0; wb0 = *(const float4*)(wp0 + 4);
        wa1 = *(const float4*)wp1; wb1 = *(const float4*)(wp1 + 4);
    }
    if (t < 128) *(bf16x8*)&As[0][srow][8 * skg] = pack8(xa, xb);
    *(bf16x8*)&Bs[0][srow][8 * skg]      = pack8(wa0, wb0);
    *(bf16x8*)&Bs[0][srow + 32][8 * skg] = pack8(wa1, wb1);
    __syncthreads();

    f32x4 acc = {};
    #pragma unroll
    for (int i = 0; i < 4; ++i) {
        const int cur = i & 1, nxt = cur ^ 1;
        if (i < 3) {                         // issue next-tile loads first
            const int k0 = (i + 1) * 64;
            if (t < 128) {
                const float* xp = X + (r0 + srow) * 256 + k0 + 8 * skg;
                xa = *(const float4*)xp; xb = *(const float4*)(xp + 4);
            }
            const float* wp0 = W + (c0 + srow) * 256 + k0 + 8 * skg;
            const float* wp1 = wp0 + 32 * 256;
            wa0 = *(const float4*)wp0; wb0 = *(const float4*)(wp0 + 4);
            wa1 = *(const float4*)wp1; wb1 = *(const float4*)(wp1 + 4);
        }
        #pragma unroll
        for (int kh = 0; kh < 2; ++kh) {
            bf16x8 a  = *(bf16x8*)&As[cur][mrow][32 * kh + 8 * quad];
            bf16x8 bf = *(bf16x8*)&Bs[cur][wc + mrow][32 * kh + 8 * quad];
            acc = __builtin_amdgcn_mfma_f32_16x16x32_bf16(a, bf, acc, 0, 0, 0);
        }
        if (i < 3) {
            if (t < 128) *(bf16x8*)&As[nxt][srow][8 * skg] = pack8(xa, xb);
            *(bf16x8*)&Bs[nxt][srow][8 * skg]      = pack8(wa0, wb0);
            *(bf16x8*)&Bs[nxt][srow + 32][8 * skg] = pack8(wa1, wb1);
        }
        __syncthreads();
    }

    const int col  = c0 + wc + mrow;
    const float bb = bias[col];
    const int head = col >> 2;
    const int qbase = lane & ~3;
    #pragma unroll
    for (int reg = 0; reg < 4; ++reg) {
        const int row = r0 + quad * 4 + reg;
        float v = acc[reg] + bb;
        float s = v * v;
        s += __shfl_xor(s, 1, 64);
        s += __shfl_xor(s, 2, 64);
        float q = v * (1.f / (sqrtf(s) + EPS));
        float q0 = __shfl(q, qbase + 0, 64);
        float q1 = __shfl(q, qbase + 1, 64);
        float q2 = __shfl(q, qbase + 2, 64);
        float q3 = __shfl(q, qbase + 3, 64);
        bf16x4 p;
        p[0] = f2bf(q * q0); p[1] = f2bf(q * q1);
        p[2] = f2bf(q * q2); p[3] = f2bf(q * q3);
        *(bf16x4*)(Eo + row * 1024 + head * 16 + (col & 3) * 4) = p;
    }
}

// ---------------------------------------------------------------------------
// K2: E = exp(dot/1024) bf16, E^T, partial row sums rs[row][32].
// Tile 16(n) x 64(m), 4 waves, kt=64, K=1024.  grid (32, 8, 2) = 512 blocks.
// Double-buffered LDS, one barrier per K-step.
// ---------------------------------------------------------------------------
__global__ __launch_bounds__(256, 2) void logits_kernel(
    const short* __restrict__ expq, short* __restrict__ E,
    short* __restrict__ ET, float* __restrict__ rs)
{
    const int b  = blockIdx.z;
    const int r0 = blockIdx.x * 16;
    const int c0 = blockIdx.y * 64;
    const int t = threadIdx.x, lane = t & 63, wave = t >> 6;
    const int wc = 16 * wave;
    const int mrow = lane & 15, quad = lane >> 4;

    __shared__ __align__(16) short As[2][16][72];
    __shared__ __align__(16) short Bs[2][64][72];

    const short* Ab = expq + (b * 512 + r0) * 1024;
    const short* Bb = expq + (1024 + b * 512 + c0) * 1024;
    const int srow = t >> 3, skg = t & 7;

    bf16x8 av, b0v, b1v;
    if (t < 128) av = *(const bf16x8*)(Ab + srow * 1024 + 8 * skg);
    b0v = *(const bf16x8*)(Bb + srow * 1024 + 8 * skg);
    b1v = *(const bf16x8*)(Bb + (srow + 32) * 1024 + 8 * skg);
    if (t < 128) *(bf16x8*)&As[0][srow][8 * skg] = av;
    *(bf16x8*)&Bs[0][srow][8 * skg]      = b0v;
    *(bf16x8*)&Bs[0][srow + 32][8 * skg] = b1v;
    __syncthreads();

    f32x4 acc = {};
    #pragma unroll
    for (int i = 0; i < 16; ++i) {
        const int cur = i & 1, nxt = cur ^ 1;
        if (i < 15) {
            const int k0 = (i + 1) * 64;
            if (t < 128) av = *(const bf16x8*)(Ab + srow * 1024 + k0 + 8 * skg);
            b0v = *(const bf16x8*)(Bb + srow * 1024 + k0 + 8 * skg);
            b1v = *(const bf16x8*)(Bb + (srow + 32) * 1024 + k0 + 8 * skg);
        }
        #pragma unroll
        for (int kh = 0; kh < 2; ++kh) {
            bf16x8 a  = *(bf16x8*)&As[cur][mrow][32 * kh + 8 * quad];
            bf16x8 bf = *(bf16x8*)&Bs[cur][wc + mrow][32 * kh + 8 * quad];
            acc = __builtin_amdgcn_mfma_f32_16x16x32_bf16(a, bf, acc, 0, 0, 0);
        }
        if (i < 15) {
            if (t < 128) *(bf16x8*)&As[nxt][srow][8 * skg] = av;
            *(bf16x8*)&Bs[nxt][srow][8 * skg]      = b0v;
            *(bf16x8*)&Bs[nxt][srow + 32][8 * skg] = b1v;
        }
        __syncthreads();
    }

    float e[4];
    bf16x4 pe;
    const int col = c0 + wc + mrow;
    #pragma unroll
    for (int reg = 0; reg < 4; ++reg) {
        e[reg]  = __expf(acc[reg] * (1.f / 1024.f));
        pe[reg] = f2bf(e[reg]);
        E[(b * 512 + r0 + quad * 4 + reg) * 512 + col] = pe[reg];
    }
    // transposed store: 4 consecutive rows -> one bf16x4
    *(bf16x4*)(ET + (b * 512 + col) * 512 + r0 + quad * 4) = pe;
    // partial sums over this wave's 16 cols
    #pragma unroll
    for (int reg = 0; reg < 4; ++reg) {
        float p = e[reg];
        p += __shfl_xor(p, 1, 64);
        p += __shfl_xor(p, 2, 64);
        p += __shfl_xor(p, 4, 64);
        p += __shfl_xor(p, 8, 64);
        if (mrow == 0)
            rs[(b * 512 + r0 + quad * 4 + reg) * 32 + (c0 >> 4) + wave] = p;
    }
}

// ---------------------------------------------------------------------------
// K3: outputs.  A-operands (E / ET) loaded DIRECT from global (fragment
// layout); only B (features, fp32->bf16 transpose) staged in LDS (dbuf,
// one barrier/step).  rinv folded into B-staging for which=1, epilogue for
// which=0.  Tile 16 x 64(d), kt=64, K=512.  grid (32, 4, 4) = 512 blocks.
// ---------------------------------------------------------------------------
__global__ __launch_bounds__(256, 2) void out_kernel(
    const float* __restrict__ vis, const float* __restrict__ txt,
    const short* __restrict__ E, const short* __restrict__ ET,
    const float* __restrict__ rs, const float* __restrict__ hptr,
    float* __restrict__ outv, float* __restrict__ outt)
{
    const int z = blockIdx.z;
    const int b = z & 1, which = z >> 1;
    const int r0 = blockIdx.x * 16;
    const int c0 = blockIdx.y * 64;
    const int t = threadIdx.x, lane = t & 63, wave = t >> 6;
    const int wc = 16 * wave;
    const int mrow = lane & 15, quad = lane >> 4;
    const float hv = hptr[0];

    const short* Ab   = (which ? ET : E) + (b * 512 + r0) * 512;
    const float* S    = (which ? vis : txt) + b * 512 * 256;
    const float* base = (which ? txt : vis) + (b * 512 + r0) * 256;
    float*       out  = (which ? outt : outv) + (b * 512 + r0) * 256;

    __shared__ __align__(16) short Bs[2][64][72];
    __shared__ float rinv_s[512];

    // prologue: softmax denominators
    if (which == 0) {
        if (t < 16) {
            const float* p = rs + (b * 512 + r0 + t) * 32;
            float s = 0.f;
            #pragma unroll
            for (int i = 0; i < 32; ++i) s += p[i];
            rinv_s[t] = 1.f / s;                  // local 16 rows
        }
    } else {
        #pragma unroll
        for (int u = 0; u < 2; ++u) {
            const int row = t + 256 * u;
            const float* p = rs + (b * 512 + row) * 32;
            float s = 0.f;
            #pragma unroll
            for (int i = 0; i < 32; ++i) s += p[i];
            rinv_s[row] = 1.f / s;                // full table (per-k scale)
        }
    }
    __syncthreads();

    const int kk = t >> 2, dg = t & 3;            // B staging coords
    float4 sv0, sv1, sv2, sv3;
    bf16x8 a0, a1;

    // prologue: load + write tile 0
    {
        const float* sp = S + kk * 256 + c0 + 16 * dg;
        sv0 = *(const float4*)sp;      sv1 = *(const float4*)(sp + 4);
        sv2 = *(const float4*)(sp + 8); sv3 = *(const float4*)(sp + 12);
        a0 = *(const bf16x8*)(Ab + mrow * 512 + 8 * quad);
        a1 = *(const bf16x8*)(Ab + mrow * 512 + 32 + 8 * quad);
        const float scl = which ? rinv_s[kk] : 1.f;
        const float f[16] = { sv0.x, sv0.y, sv0.z, sv0.w, sv1.x, sv1.y, sv1.z, sv1.w,
                              sv2.x, sv2.y, sv2.z, sv2.w, sv3.x, sv3.y, sv3.z, sv3.w };
        #pragma unroll
        for (int i = 0; i < 16; ++i) Bs[0][16 * dg + i][kk] = f2bf(f[i] * scl);
    }
    __syncthreads();

    f32x4 acc = {};
    #pragma unroll
    for (int i = 0; i < 8; ++i) {
        const int cur = i & 1;
        bf16x8 ca0 = a0, ca1 = a1;
        if (i < 7) {
            const int k0 = (i + 1) * 64;
            const float* sp = S + (k0 + kk) * 256 + c0 + 16 * dg;
            sv0 = *(const float4*)sp;      sv1 = *(const float4*)(sp + 4);
            sv2 = *(const float4*)(sp + 8); sv3 = *(const float4*)(sp + 12);
            a0 = *(const bf16x8*)(Ab + mrow * 512 + k0 + 8 * quad);
            a1 = *(const bf16x8*)(Ab + mrow * 512 + k0 + 32 + 8 * quad);
        }
        {
            bf16x8 b0 = *(bf16x8*)&Bs[cur][wc + mrow][8 * quad];
            bf16x8 b1 = *(bf16x8*)&Bs[cur][wc + mrow][32 + 8 * quad];
            acc = __builtin_amdgcn_mfma_f32_16x16x32_bf16(ca0, b0, acc, 0, 0, 0);
            acc = __builtin_amdgcn_mfma_f32_16x16x32_bf16(ca1, b1, acc, 0, 0, 0);
        }
        if (i < 7) {
            const int k0 = (i + 1) * 64;
            const float scl = which ? rinv_s[k0 + kk] : 1.f;
            const float f[16] = { sv0.x, sv0.y, sv0.z, sv0.w, sv1.x, sv1.y, sv1.z, sv1.w,
                                  sv2.x, sv2.y, sv2.z, sv2.w, sv3.x, sv3.y, sv3.z, sv3.w };
            #pragma unroll
            for (int u = 0; u < 16; ++u) Bs[cur ^ 1][16 * dg + u][kk] = f2bf(f[u] * scl);
        }
        __syncthreads();
    }

    const int col = c0 + wc + mrow;
    #pragma unroll
    for (int reg = 0; reg < 4; ++reg) {
        const int row = quad * 4 + reg;
        const float scale = which ? hv : hv * rinv_s[row];
        out[row * 256 + col] = fmaf(scale, acc[reg], base[row * 256 + col]);
    }
}

// ---------------------------------------------------------------------------
extern "C" void kernel_launch(void* const* d_in, const int* in_sizes, int n_in,
                              void* d_out, int out_size, void* d_ws, size_t ws_size,
                              hipStream_t stream)
{
    const float* vis = (const float*)d_in[0];
    const float* txt = (const float*)d_in[1];
    const float* Wv  = (const float*)d_in[2];
    const float* bv  = (const float*)d_in[3];
    const float* Wt  = (const float*)d_in[4];
    const float* bt  = (const float*)d_in[5];
    const float* h   = (const float*)d_in[6];

    float* outv = (float*)d_out;                  // 2*512*256
    float* outt = (float*)d_out + 2 * 512 * 256;

    short* expq = (short*)d_ws;                   // 2048 x 1024 bf16 (4 MB)
    short* E    = expq + 2048 * 1024;             // 1024 x 512 bf16 (1 MB)
    short* ET   = E + 1024 * 512;                 // 1024 x 512 bf16 (1 MB)
    float* rs   = (float*)(ET + 1024 * 512);      // 1024 x 32 fp32 (128 KB)

    proj_expand_kernel<<<dim3(64, 4, 2), 256, 0, stream>>>(vis, txt, Wv, bv, Wt, bt, expq);
    logits_kernel<<<dim3(32, 8, 2), 256, 0, stream>>>(expq, E, ET, rs);
    out_kernel<<<dim3(32, 4, 4), 256, 0, stream>>>(vis, txt, E, ET, rs, h, outv, outt);
}